// Round 9
// baseline (460.891 us; speedup 1.0000x reference)
//
#include <hip/hip_runtime.h>
#include <math.h>
#include <float.h>

#define B_ 2
#define S_ 2048
#define D_ 1024
#define H_ 16
#define V_ 4096
#define NZ_ 10
#define BS_ (B_ * S_)     // 4096 rows

typedef __attribute__((ext_vector_type(8))) __bf16 bf16x8;
typedef __attribute__((ext_vector_type(4))) float f32x4;

#define MFMA16(a, b, c) __builtin_amdgcn_mfma_f32_16x16x32_bf16((a), (b), (c), 0, 0, 0)

__device__ __forceinline__ unsigned short f2bf(float f) {
  unsigned u = __builtin_bit_cast(unsigned, f);
  u = (u + 0x7FFFu + ((u >> 16) & 1u)) >> 16;
  return (unsigned short)u;
}
__device__ __forceinline__ float bf2f(unsigned short h) {
  unsigned u = ((unsigned)h) << 16;
  return __builtin_bit_cast(float, u);
}

// ---------------------------------------------------------------------------
// fp32 -> bf16 hi (+ optional lo residual) split (x only)
// ---------------------------------------------------------------------------
template <bool WLO>
__global__ __launch_bounds__(256) void split_kernel(const float* __restrict__ in,
                                                    unsigned short* __restrict__ hi,
                                                    unsigned short* __restrict__ lo) {
  int i = (blockIdx.x * 256 + threadIdx.x) * 4;
  float4 x = *(const float4*)(in + i);
  ushort4 h;
  h.x = f2bf(x.x); h.y = f2bf(x.y); h.z = f2bf(x.z); h.w = f2bf(x.w);
  *(ushort4*)(hi + i) = h;
  if (WLO) {
    ushort4 l;
    l.x = f2bf(x.x - bf2f(h.x));
    l.y = f2bf(x.y - bf2f(h.y));
    l.z = f2bf(x.z - bf2f(h.z));
    l.w = f2bf(x.w - bf2f(h.w));
    *(ushort4*)(lo + i) = l;
  }
}

// ---------------------------------------------------------------------------
// All 4 weight splits in one launch. wq/wk: hi+lo; wv/wo: hi only.
// ---------------------------------------------------------------------------
__global__ __launch_bounds__(256) void split_w4_kernel(
    const float* __restrict__ wq, const float* __restrict__ wk,
    const float* __restrict__ wv, const float* __restrict__ wo,
    unsigned short* __restrict__ wqh, unsigned short* __restrict__ wql,
    unsigned short* __restrict__ wkh, unsigned short* __restrict__ wkl,
    unsigned short* __restrict__ wvh, unsigned short* __restrict__ woh) {
  int idx = (blockIdx.x * 256 + threadIdx.x) * 4;
  int w = idx >> 20;                      // D*D = 2^20
  int off = idx & ((1 << 20) - 1);
  const float* src; unsigned short* hi; unsigned short* lo;
  if (w == 0)      { src = wq; hi = wqh; lo = wql; }
  else if (w == 1) { src = wk; hi = wkh; lo = wkl; }
  else if (w == 2) { src = wv; hi = wvh; lo = nullptr; }
  else             { src = wo; hi = woh; lo = nullptr; }
  float4 x = *(const float4*)(src + off);
  ushort4 h;
  h.x = f2bf(x.x); h.y = f2bf(x.y); h.z = f2bf(x.z); h.w = f2bf(x.w);
  *(ushort4*)(hi + off) = h;
  if (lo) {
    ushort4 l;
    l.x = f2bf(x.x - bf2f(h.x));
    l.y = f2bf(x.y - bf2f(h.y));
    l.z = f2bf(x.z - bf2f(h.z));
    l.w = f2bf(x.w - bf2f(h.w));
    *(ushort4*)(lo + off) = l;
  }
}

// ---------------------------------------------------------------------------
// omega (V x V fp32) -> bit table obit[V][64] (uint64). bit=1: NOT masked.
// ---------------------------------------------------------------------------
__global__ __launch_bounds__(256) void omega_pack_kernel(const float* __restrict__ omega,
                                                         unsigned long long* __restrict__ obit) {
  int e = blockIdx.x * 256 + threadIdx.x;
  bool ok = omega[e] != 0.f;
  unsigned long long mask = __ballot(ok);
  if ((threadIdx.x & 63) == 0) obit[e >> 6] = mask;
}

// ---------------------------------------------------------------------------
// MFMA GEMM: C[M,N] = A[M,K] * W[N,K]^T + bias[N]
// SPLIT=3: hi/lo split inputs (fp32-accurate). SPLIT=1: plain bf16.
// Outputs (each optional): C fp32, Chi bf16, Clo bf16 residual (needs Chi).
// ---------------------------------------------------------------------------
template <int SPLIT>
__global__ __launch_bounds__(256) void mfma_gemm(const unsigned short* __restrict__ Ah,
                                                 const unsigned short* __restrict__ Al,
                                                 const unsigned short* __restrict__ Wh,
                                                 const unsigned short* __restrict__ Wl,
                                                 const float* __restrict__ bias,
                                                 float* __restrict__ C,
                                                 unsigned short* __restrict__ Chi,
                                                 unsigned short* __restrict__ Clo,
                                                 int M, int N, int K) {
  constexpr int NTILES = (SPLIT == 3) ? 4 : 2;
  __shared__ unsigned short tiles[NTILES * 4096];   // [tile][128 rows][32 cols]
  const int t = threadIdx.x;
  const int wave = t >> 6, lane = t & 63;
  const int i0 = blockIdx.y * 128, n0 = blockIdx.x * 128;
  const int wm = wave >> 1, wn = wave & 1;
  const int m = lane & 15, quad = lane >> 4;

  const unsigned short* gb[NTILES];
  gb[0] = Ah + (size_t)i0 * K;
  gb[1] = Wh + (size_t)n0 * K;
  if (SPLIT == 3) {
    gb[2] = Al + (size_t)i0 * K;
    gb[3] = Wl + (size_t)n0 * K;
  }

  f32x4 acc[4][4] = {};

  for (int k0 = 0; k0 < K; k0 += 32) {
    __syncthreads();
    for (int cc = wave; cc < NTILES * 8; cc += 4) {
      int tile = cc >> 3, c = cc & 7;
      int s = (c << 6) + lane;
      int row = s >> 2;
      int cq = (s & 3) ^ ((s >> 3) & 3);
      const unsigned short* g = gb[tile] + (size_t)row * K + k0 + (cq << 3);
      unsigned short* l = &tiles[tile * 4096 + (s << 3)];
      __builtin_amdgcn_global_load_lds((const __attribute__((address_space(1))) void*)g,
                                       (__attribute__((address_space(3))) void*)l,
                                       16, 0, 0);
    }
    __syncthreads();

    bf16x8 afh[4], bfh[4];
#pragma unroll
    for (int mt = 0; mt < 4; ++mt) {
      int r = wm * 64 + mt * 16 + m;
      afh[mt] = *(const bf16x8*)&tiles[0 * 4096 + r * 32 + ((quad ^ ((r >> 1) & 3)) << 3)];
    }
#pragma unroll
    for (int nt = 0; nt < 4; ++nt) {
      int r = wn * 64 + nt * 16 + m;
      bfh[nt] = *(const bf16x8*)&tiles[1 * 4096 + r * 32 + ((quad ^ ((r >> 1) & 3)) << 3)];
    }
    if (SPLIT == 3) {
      bf16x8 afl[4], bfl[4];
#pragma unroll
      for (int mt = 0; mt < 4; ++mt) {
        int r = wm * 64 + mt * 16 + m;
        afl[mt] = *(const bf16x8*)&tiles[2 * 4096 + r * 32 + ((quad ^ ((r >> 1) & 3)) << 3)];
      }
#pragma unroll
      for (int nt = 0; nt < 4; ++nt) {
        int r = wn * 64 + nt * 16 + m;
        bfl[nt] = *(const bf16x8*)&tiles[3 * 4096 + r * 32 + ((quad ^ ((r >> 1) & 3)) << 3)];
      }
#pragma unroll
      for (int mt = 0; mt < 4; ++mt)
#pragma unroll
        for (int nt = 0; nt < 4; ++nt) {
          acc[mt][nt] = MFMA16(afh[mt], bfh[nt], acc[mt][nt]);
          acc[mt][nt] = MFMA16(afl[mt], bfh[nt], acc[mt][nt]);
          acc[mt][nt] = MFMA16(afh[mt], bfl[nt], acc[mt][nt]);
        }
    } else {
#pragma unroll
      for (int mt = 0; mt < 4; ++mt)
#pragma unroll
        for (int nt = 0; nt < 4; ++nt)
          acc[mt][nt] = MFMA16(afh[mt], bfh[nt], acc[mt][nt]);
    }
  }

  float bvv[4];
#pragma unroll
  for (int nt = 0; nt < 4; ++nt) bvv[nt] = bias[n0 + wn * 64 + nt * 16 + m];
#pragma unroll
  for (int mt = 0; mt < 4; ++mt) {
    int rbase = i0 + wm * 64 + mt * 16 + quad * 4;
#pragma unroll
    for (int nt = 0; nt < 4; ++nt) {
      int col = n0 + wn * 64 + nt * 16 + m;
#pragma unroll
      for (int r = 0; r < 4; ++r) {
        float val = acc[mt][nt][r] + bvv[nt];
        size_t idx = (size_t)(rbase + r) * N + col;
        if (C) C[idx] = val;
        if (Chi) {
          unsigned short hv = f2bf(val);
          Chi[idx] = hv;
          if (Clo) Clo[idx] = f2bf(val - bf2f(hv));
        }
      }
    }
  }
}

// ---------------------------------------------------------------------------
// ts8[b][g][d] = sum over j in [8g, 8g+8) of v[b][j][d]  (bf16 v input)
// ---------------------------------------------------------------------------
__global__ void ts8_kernel(const unsigned short* __restrict__ vh, float* __restrict__ ts8) {
  int idx = blockIdx.x * 256 + threadIdx.x;  // (b*256+g)*D_ + d
  int d = idx % D_;
  int bg = idx / D_;
  int g = bg % 256;
  int b = bg / 256;
  const unsigned short* p = vh + (size_t)(b * S_ + g * 8) * D_ + d;
  float s = 0.f;
#pragma unroll
  for (int j = 0; j < 8; ++j) s += bf2f(p[(size_t)j * D_]);
  ts8[idx] = s;
}

// ---------------------------------------------------------------------------
// ts64[b][T][d] = sum of 8 ts8 groups   (T in [0,32))
// ---------------------------------------------------------------------------
__global__ void ts64_kernel(const float* __restrict__ ts8, float* __restrict__ ts64) {
  int idx = blockIdx.x * 256 + threadIdx.x;  // (b*32+T)*D_ + d
  int d = idx % D_;
  int bT = idx / D_;
  int T = bT % 32;
  int b = bT / 32;
  float s = 0.f;
#pragma unroll
  for (int u = 0; u < 8; ++u) s += ts8[((size_t)b * 256 + T * 8 + u) * D_ + d];
  ts64[idx] = s;
}

// ---------------------------------------------------------------------------
// tsp[b][T][d] = sum of ts64[b][T'<T][d]   (T in [0,33]; T=32 -> total)
// fully parallel (old version ran on 8 blocks -> latency-serial)
// ---------------------------------------------------------------------------
__global__ void tsp2_kernel(const float* __restrict__ ts64, float* __restrict__ tsp) {
  int idx = blockIdx.x * 256 + threadIdx.x;  // (b*33+T)*D_ + d
  int d = idx % D_;
  int bT = idx / D_;
  int T = bT % 33;
  int b = bT / 33;
  float s = 0.f;
  for (int u = 0; u < T; ++u) s += ts64[((size_t)b * 32 + u) * D_ + d];
  tsp[idx] = s;
}

// ---------------------------------------------------------------------------
// bandmask[b*S+i] bit dlt = 1 iff j=i-dlt >= 0 and omega unmasked (via obit)
// ---------------------------------------------------------------------------
__global__ __launch_bounds__(256) void bandmask_kernel(const int* __restrict__ ids,
                                                       const unsigned long long* __restrict__ obit,
                                                       unsigned long long* __restrict__ bm) {
  int row = blockIdx.x * 4 + (threadIdx.x >> 6);
  int lane = threadIdx.x & 63;
  int b = row / S_, i = row % S_;
  int idi = ids[row];
  int j = i - lane;
  bool ok = false;
  if (j >= 0) {
    int idj = ids[b * S_ + j];
    ok = (obit[((size_t)idi << 6) + (idj >> 6)] >> (idj & 63)) & 1ull;
  }
  unsigned long long mask = __ballot(ok);
  if (lane == 0) bm[row] = mask;
}

// ---------------------------------------------------------------------------
// farsum (bf16 out) / c0 — prefix hierarchy + bit-packed omega
// ---------------------------------------------------------------------------
__global__ __launch_bounds__(256) void farsum_kernel(const unsigned short* __restrict__ vh,
                                                     const float* __restrict__ ts8,
                                                     const float* __restrict__ tsp,
                                                     const int* __restrict__ ids,
                                                     const unsigned long long* __restrict__ obit,
                                                     unsigned short* __restrict__ farsum,
                                                     int* __restrict__ c0) {
  const int b = blockIdx.x / S_;
  const int i = blockIdx.x % S_;
  const int t = threadIdx.x;
  if (i < 64) {
    if (t == 0) c0[blockIdx.x] = 0;
    return;
  }
  const int jmax = i - 64;
  const int F = jmax + 1;
  const int d0 = t * 4;
  const int T = F >> 6;
  const int G8 = (F & 63) >> 3;

  float4 acc = *(const float4*)(tsp + ((size_t)b * 33 + T) * D_ + d0);
  for (int u = 0; u < G8; ++u) {
    float4 x = *(const float4*)(ts8 + ((size_t)b * 256 + T * 8 + u) * D_ + d0);
    acc.x += x.x; acc.y += x.y; acc.z += x.z; acc.w += x.w;
  }
  for (int j = (T << 6) + (G8 << 3); j <= jmax; ++j) {
    ushort4 x = *(const ushort4*)(vh + ((size_t)(b * S_) + j) * D_ + d0);
    acc.x += bf2f(x.x); acc.y += bf2f(x.y);
    acc.z += bf2f(x.z); acc.w += bf2f(x.w);
  }

  __shared__ int list[256];
  __shared__ int cnt;
  const int idi = ids[b * S_ + i];
  const unsigned long long* orow = obit + ((size_t)idi << 6);
  int nmask = 0;
  for (int base = 0; base < F; base += 256) {
    if (t == 0) cnt = 0;
    __syncthreads();
    int j = base + t;
    if (j <= jmax) {
      int idj = ids[b * S_ + j];
      if (!((orow[idj >> 6] >> (idj & 63)) & 1ull)) list[atomicAdd(&cnt, 1)] = j;
    }
    __syncthreads();
    int c = cnt;
    nmask += c;
    for (int mm = 0; mm < c; ++mm) {
      int jm = list[mm];
      ushort4 x = *(const ushort4*)(vh + ((size_t)(b * S_) + jm) * D_ + d0);
      acc.x -= bf2f(x.x); acc.y -= bf2f(x.y);
      acc.z -= bf2f(x.z); acc.w -= bf2f(x.w);
    }
    __syncthreads();
  }
  ushort4 o;
  o.x = f2bf(acc.x); o.y = f2bf(acc.y); o.z = f2bf(acc.z); o.w = f2bf(acc.w);
  *(ushort4*)(farsum + (size_t)(b * S_ + i) * D_ + d0) = o;
  if (t == 0) c0[blockIdx.x] = F - nmask;
}

// ---------------------------------------------------------------------------
// MFMA flash-style banded attention (unchanged from R7/R8).
// ---------------------------------------------------------------------------
__global__ __launch_bounds__(256) void attn3_kernel(
    const unsigned short* __restrict__ qh, const unsigned short* __restrict__ ql,
    const unsigned short* __restrict__ kh, const unsigned short* __restrict__ kl,
    const unsigned short* __restrict__ vh, const unsigned short* __restrict__ farsum,
    const int* __restrict__ c0arr, const float* __restrict__ tsp,
    const unsigned long long* __restrict__ bm, const float* __restrict__ gamma,
    unsigned short* __restrict__ out) {
  const int h = blockIdx.x, i0 = blockIdx.y * 64, b = blockIdx.z;
  __shared__ unsigned short Qhs[64][72], Qls[64][72], Khs[64][72], KlP[64][72], Vt[64][72];
  __shared__ float mrow[64], lrow[64], arow[64], Mband[64];
  __shared__ float rmaxw[4][32], rsumw[4][32];
  __shared__ unsigned long long bmr[64];
  __shared__ int c0r[64];
  const int t = threadIdx.x, lane = t & 63, wave = t >> 6;
  const int m = lane & 15, quad = lane >> 4;
  const int wm = wave >> 1, wn = wave & 1;

  for (int c = t; c < 1024; c += 256) {
    int r = c >> 4, d4 = (c & 15) << 2;
    size_t g = ((size_t)(b * S_) + i0 + r) * D_ + h * 64 + d4;
    *(ushort4*)&Qhs[r][d4] = *(const ushort4*)(qh + g);
    *(ushort4*)&Qls[r][d4] = *(const ushort4*)(ql + g);
  }
  if (t < 64) {
    float delta = (float)t;
    float ld = logf(delta + 1.f);
    float cs = 0.f;
#pragma unroll
    for (int z = 0; z < NZ_; ++z) cs += cosf(gamma[z] * ld);
    Mband[t] = expf(-delta) * cs * 0.125f;
    int grow = b * S_ + i0 + t;
    bmr[t] = bm[grow];
    int c0v = c0arr[grow];
    c0r[t] = c0v;
    mrow[t] = (c0v > 0) ? 0.f : -FLT_MAX;
    lrow[t] = 0.f;
  }
  f32x4 accO[2][2] = {};

  for (int pass = 0; pass < 2; ++pass) {
    const int jt0 = i0 + (pass - 1) * 64;
    if (jt0 < 0) continue;
    __syncthreads();
    for (int c = t; c < 1024; c += 256) {
      int r = c >> 4, d4 = (c & 15) << 2;
      size_t g = ((size_t)(b * S_) + jt0 + r) * D_ + h * 64 + d4;
      *(ushort4*)&Khs[r][d4] = *(const ushort4*)(kh + g);
      *(ushort4*)&KlP[r][d4] = *(const ushort4*)(kl + g);
      ushort4 vv = *(const ushort4*)(vh + g);
      Vt[d4 + 0][r] = vv.x; Vt[d4 + 1][r] = vv.y;
      Vt[d4 + 2][r] = vv.z; Vt[d4 + 3][r] = vv.w;
    }
    __syncthreads();
    f32x4 accS[2][2] = {};
#pragma unroll
    for (int kc = 0; kc < 2; ++kc) {
      bf16x8 aH[2], aL[2], bH[2], bL[2];
#pragma unroll
      for (int mt = 0; mt < 2; ++mt) {
        aH[mt] = *(const bf16x8*)&Qhs[wm * 32 + mt * 16 + m][kc * 32 + quad * 8];
        aL[mt] = *(const bf16x8*)&Qls[wm * 32 + mt * 16 + m][kc * 32 + quad * 8];
      }
#pragma unroll
      for (int nt = 0; nt < 2; ++nt) {
        bH[nt] = *(const bf16x8*)&Khs[wn * 32 + nt * 16 + m][kc * 32 + quad * 8];
        bL[nt] = *(const bf16x8*)&KlP[wn * 32 + nt * 16 + m][kc * 32 + quad * 8];
      }
#pragma unroll
      for (int mt = 0; mt < 2; ++mt)
#pragma unroll
        for (int nt = 0; nt < 2; ++nt) {
          accS[mt][nt] = MFMA16(aH[mt], bH[nt], accS[mt][nt]);
          accS[mt][nt] = MFMA16(aL[mt], bH[nt], accS[mt][nt]);
          accS[mt][nt] = MFMA16(aH[mt], bL[nt], accS[mt][nt]);
        }
    }
    float rmx[2][4];
#pragma unroll
    for (int mt = 0; mt < 2; ++mt)
#pragma unroll
      for (int r = 0; r < 4; ++r) rmx[mt][r] = -FLT_MAX;
#pragma unroll
    for (int mt = 0; mt < 2; ++mt)
#pragma unroll
      for (int nt = 0; nt < 2; ++nt)
#pragma unroll
        for (int r = 0; r < 4; ++r) {
          int il = wm * 32 + mt * 16 + quad * 4 + r;
          int jl = wn * 32 + nt * 16 + m;
          int dlt = (pass == 0) ? (il + 64 - jl) : (il - jl);
          float s = -FLT_MAX;
          if (dlt >= 0 && dlt < 64 && ((bmr[il] >> dlt) & 1ull))
            s = accS[mt][nt][r] * Mband[dlt];
          accS[mt][nt][r] = s;
          rmx[mt][r] = fmaxf(rmx[mt][r], s);
        }
#pragma unroll
    for (int off = 1; off < 16; off <<= 1)
#pragma unroll
      for (int mt = 0; mt < 2; ++mt)
#pragma unroll
        for (int r = 0; r < 4; ++r)
          rmx[mt][r] = fmaxf(rmx[mt][r], __shfl_xor(rmx[mt][r], off));
    if (m == 0)
#pragma unroll
      for (int mt = 0; mt < 2; ++mt)
#pragma unroll
        for (int r = 0; r < 4; ++r)
          rmaxw[wave][mt * 16 + quad * 4 + r] = rmx[mt][r];
    __syncthreads();
    if (t < 64) {
      int wmw = t >> 5, idx = t & 31;
      float tmax = fmaxf(rmaxw[wmw * 2][idx], rmaxw[wmw * 2 + 1][idx]);
      float mold = mrow[t], mnew = fmaxf(mold, tmax);
      arow[t] = expf(mold - mnew);
      mrow[t] = mnew;
    }
    __syncthreads();
    float rs[2][4] = {};
#pragma unroll
    for (int mt = 0; mt < 2; ++mt)
#pragma unroll
      for (int nt = 0; nt < 2; ++nt)
#pragma unroll
        for (int r = 0; r < 4; ++r) {
          int il = wm * 32 + mt * 16 + quad * 4 + r;
          int jl = wn * 32 + nt * 16 + m;
          float s = accS[mt][nt][r];
          float p = (s > -1e37f) ? expf(s - mrow[il]) : 0.f;
          rs[mt][r] += p;
          KlP[il][jl] = f2bf(p);
        }
#pragma unroll
    for (int off = 1; off < 16; off <<= 1)
#pragma unroll
      for (int mt = 0; mt < 2; ++mt)
#pragma unroll
        for (int r = 0; r < 4; ++r)
          rs[mt][r] += __shfl_xor(rs[mt][r], off);
    if (m == 0)
#pragma unroll
      for (int mt = 0; mt < 2; ++mt)
#pragma unroll
        for (int r = 0; r < 4; ++r)
          rsumw[wave][mt * 16 + quad * 4 + r] = rs[mt][r];
#pragma unroll
    for (int mt = 0; mt < 2; ++mt)
#pragma unroll
      for (int r = 0; r < 4; ++r) {
        float al = arow[wm * 32 + mt * 16 + quad * 4 + r];
        accO[mt][0][r] *= al;
        accO[mt][1][r] *= al;
      }
    __syncthreads();
    if (t < 64) {
      int wmw = t >> 5, idx = t & 31;
      lrow[t] = lrow[t] * arow[t] + rsumw[wmw * 2][idx] + rsumw[wmw * 2 + 1][idx];
    }
#pragma unroll
    for (int kc = 0; kc < 2; ++kc) {
      bf16x8 aP[2], bV[2];
#pragma unroll
      for (int mt = 0; mt < 2; ++mt)
        aP[mt] = *(const bf16x8*)&KlP[wm * 32 + mt * 16 + m][kc * 32 + quad * 8];
#pragma unroll
      for (int nt = 0; nt < 2; ++nt)
        bV[nt] = *(const bf16x8*)&Vt[wn * 32 + nt * 16 + m][kc * 32 + quad * 8];
#pragma unroll
      for (int mt = 0; mt < 2; ++mt)
#pragma unroll
        for (int nt = 0; nt < 2; ++nt)
          accO[mt][nt] = MFMA16(aP[mt], bV[nt], accO[mt][nt]);
    }
  }
  __syncthreads();
#pragma unroll
  for (int mt = 0; mt < 2; ++mt)
#pragma unroll
    for (int r = 0; r < 4; ++r) {
      int il = wm * 32 + mt * 16 + quad * 4 + r;
      int gi = i0 + il;
      float mv = mrow[il], l = lrow[il];
      int C0 = c0r[il];
      float efar = (C0 > 0) ? expf(-mv) : 0.f;
      float denom = l + (float)C0 * efar;
      bool degen = (l == 0.f && C0 == 0);
      if (degen) denom = (float)S_;
      float inv = 1.f / denom;
#pragma unroll
      for (int nt = 0; nt < 2; ++nt) {
        int d = wn * 32 + nt * 16 + m;
        size_t base = ((size_t)(b * S_) + gi) * D_ + h * 64 + d;
        float o = accO[mt][nt][r];
        if (C0 > 0) o += efar * bf2f(farsum[base]);
        if (degen) o = tsp[((size_t)b * 33 + 32) * D_ + h * 64 + d];
        out[base] = f2bf(o * inv);
      }
    }
}

// ---------------------------------------------------------------------------
extern "C" void kernel_launch(void* const* d_in, const int* in_sizes, int n_in,
                              void* d_out, int out_size, void* d_ws, size_t ws_size,
                              hipStream_t stream) {
  const float* x     = (const float*)d_in[0];
  const float* wq    = (const float*)d_in[1];
  const float* bq    = (const float*)d_in[2];
  const float* wk    = (const float*)d_in[3];
  const float* bk    = (const float*)d_in[4];
  const float* wv    = (const float*)d_in[5];
  const float* bv    = (const float*)d_in[6];
  const float* wo    = (const float*)d_in[7];
  const float* bo    = (const float*)d_in[8];
  const float* omega = (const float*)d_in[9];
  const float* gamma = (const float*)d_in[10];
  const int*   ids   = (const int*)d_in[11];
  float* out = (float*)d_out;

  // Workspace ~76 MB (watermark: keep < 84 MB — R3's 96.8 MB corrupted
  // harness memory).
  char* ws = (char*)d_ws;
  const size_t SZH = (size_t)BS_ * D_ * 2;                  // 8.39 MB bf16 unit
  const size_t WH  = (size_t)D_ * D_ * 2;                   // 2.10 MB
  unsigned short* qhb = (unsigned short*)(ws);
  unsigned short* qlb = (unsigned short*)(ws + 1 * SZH);
  unsigned short* khb = (unsigned short*)(ws + 2 * SZH);
  unsigned short* klb = (unsigned short*)(ws + 3 * SZH);
  unsigned short* vhb = (unsigned short*)(ws + 4 * SZH);
  unsigned short* xl    = (unsigned short*)(ws + 5 * SZH);  // dies after K-GEMM
  unsigned short* fsumh = xl;                               // aliases xl
  unsigned short* xh    = (unsigned short*)(ws + 6 * SZH);
  unsigned short* ah    = xh;                               // attn out, after V-GEMM
  char* wp = ws + 7 * SZH;
  unsigned short* wqh = (unsigned short*)(wp);
  unsigned short* wql = (unsigned short*)(wp + 1 * WH);
  unsigned short* wkh = (unsigned short*)(wp + 2 * WH);
  unsigned short* wkl = (unsigned short*)(wp + 3 * WH);
  unsigned short* wvh = (unsigned short*)(wp + 4 * WH);
  unsigned short* woh = (unsigned short*)(wp + 5 * WH);
  char* tail = wp + 6 * WH;
  unsigned long long* obit = (unsigned long long*)tail;               // 2 MB
  float* ts8  = (float*)(tail + (size_t)V_ * 64 * 8);                 // 2.10 MB
  float* ts64 = (float*)((char*)ts8 + (size_t)B_ * 256 * D_ * 4);     // 0.26 MB
  float* tsp  = (float*)((char*)ts64 + (size_t)B_ * 32 * D_ * 4);     // 0.27 MB
  int* c0 = (int*)((char*)tsp + (size_t)B_ * 33 * D_ * 4);
  unsigned long long* bmask = (unsigned long long*)((char*)c0 + (size_t)BS_ * 4);

  dim3 gg(D_ / 128, BS_ / 128);   // (8, 32)

  split_kernel<true><<<(BS_ * D_) / 1024, 256, 0, stream>>>(x, xh, xl);
  omega_pack_kernel<<<(V_ * V_) / 256, 256, 0, stream>>>(omega, obit);
  split_w4_kernel<<<(4 * D_ * D_) / 1024, 256, 0, stream>>>(wq, wk, wv, wo,
                                                            wqh, wql, wkh, wkl, wvh, woh);

  mfma_gemm<3><<<gg, 256, 0, stream>>>(xh, xl, wqh, wql, bq, nullptr, qhb, qlb, BS_, D_, D_);
  mfma_gemm<3><<<gg, 256, 0, stream>>>(xh, xl, wkh, wkl, bk, nullptr, khb, klb, BS_, D_, D_);
  mfma_gemm<1><<<gg, 256, 0, stream>>>(xh, nullptr, wvh, nullptr, bv, nullptr, vhb, nullptr,
                                       BS_, D_, D_);

  ts8_kernel<<<(B_ * 256 * D_) / 256, 256, 0, stream>>>(vhb, ts8);
  ts64_kernel<<<(B_ * 32 * D_) / 256, 256, 0, stream>>>(ts8, ts64);
  tsp2_kernel<<<(B_ * 33 * D_) / 256, 256, 0, stream>>>(ts64, tsp);
  bandmask_kernel<<<(B_ * S_) / 4, 256, 0, stream>>>(ids, obit, bmask);
  farsum_kernel<<<B_ * S_, 256, 0, stream>>>(vhb, ts8, tsp, ids, obit, fsumh, c0);
  attn3_kernel<<<dim3(H_, S_ / 64, B_), 256, 0, stream>>>(qhb, qlb, khb, klb, vhb, fsumh, c0,
                                                          tsp, bmask, gamma, ah);

  mfma_gemm<1><<<gg, 256, 0, stream>>>(ah, nullptr, woh, nullptr, bo, out, nullptr, nullptr,
                                       BS_, D_, D_);
}

// Round 10
// 424.060 us; speedup vs baseline: 1.0869x; 1.0869x over previous
//
#include <hip/hip_runtime.h>
#include <math.h>
#include <float.h>

#define B_ 2
#define S_ 2048
#define D_ 1024
#define H_ 16
#define V_ 4096
#define NZ_ 10
#define BS_ (B_ * S_)     // 4096 rows

typedef __attribute__((ext_vector_type(8))) __bf16 bf16x8;
typedef __attribute__((ext_vector_type(4))) float f32x4;

#define MFMA16(a, b, c) __builtin_amdgcn_mfma_f32_16x16x32_bf16((a), (b), (c), 0, 0, 0)

__device__ __forceinline__ unsigned short f2bf(float f) {
  unsigned u = __builtin_bit_cast(unsigned, f);
  u = (u + 0x7FFFu + ((u >> 16) & 1u)) >> 16;
  return (unsigned short)u;
}
__device__ __forceinline__ float bf2f(unsigned short h) {
  unsigned u = ((unsigned)h) << 16;
  return __builtin_bit_cast(float, u);
}

// ---------------------------------------------------------------------------
// fp32 -> bf16 hi (+ optional lo residual) split (x only)
// ---------------------------------------------------------------------------
template <bool WLO>
__global__ __launch_bounds__(256) void split_kernel(const float* __restrict__ in,
                                                    unsigned short* __restrict__ hi,
                                                    unsigned short* __restrict__ lo) {
  int i = (blockIdx.x * 256 + threadIdx.x) * 4;
  float4 x = *(const float4*)(in + i);
  ushort4 h;
  h.x = f2bf(x.x); h.y = f2bf(x.y); h.z = f2bf(x.z); h.w = f2bf(x.w);
  *(ushort4*)(hi + i) = h;
  if (WLO) {
    ushort4 l;
    l.x = f2bf(x.x - bf2f(h.x));
    l.y = f2bf(x.y - bf2f(h.y));
    l.z = f2bf(x.z - bf2f(h.z));
    l.w = f2bf(x.w - bf2f(h.w));
    *(ushort4*)(lo + i) = l;
  }
}

// ---------------------------------------------------------------------------
// All 4 weight splits in one launch. wq/wk: hi+lo; wv/wo: hi only.
// ---------------------------------------------------------------------------
__global__ __launch_bounds__(256) void split_w4_kernel(
    const float* __restrict__ wq, const float* __restrict__ wk,
    const float* __restrict__ wv, const float* __restrict__ wo,
    unsigned short* __restrict__ wqh, unsigned short* __restrict__ wql,
    unsigned short* __restrict__ wkh, unsigned short* __restrict__ wkl,
    unsigned short* __restrict__ wvh, unsigned short* __restrict__ woh) {
  int idx = (blockIdx.x * 256 + threadIdx.x) * 4;
  int w = idx >> 20;                      // D*D = 2^20
  int off = idx & ((1 << 20) - 1);
  const float* src; unsigned short* hi; unsigned short* lo;
  if (w == 0)      { src = wq; hi = wqh; lo = wql; }
  else if (w == 1) { src = wk; hi = wkh; lo = wkl; }
  else if (w == 2) { src = wv; hi = wvh; lo = nullptr; }
  else             { src = wo; hi = woh; lo = nullptr; }
  float4 x = *(const float4*)(src + off);
  ushort4 h;
  h.x = f2bf(x.x); h.y = f2bf(x.y); h.z = f2bf(x.z); h.w = f2bf(x.w);
  *(ushort4*)(hi + off) = h;
  if (lo) {
    ushort4 l;
    l.x = f2bf(x.x - bf2f(h.x));
    l.y = f2bf(x.y - bf2f(h.y));
    l.z = f2bf(x.z - bf2f(h.z));
    l.w = f2bf(x.w - bf2f(h.w));
    *(ushort4*)(lo + off) = l;
  }
}

// ---------------------------------------------------------------------------
// omega (V x V fp32) -> bit table obit[V][64] (uint64). bit=1: NOT masked.
// ---------------------------------------------------------------------------
__global__ __launch_bounds__(256) void omega_pack_kernel(const float* __restrict__ omega,
                                                         unsigned long long* __restrict__ obit) {
  int e = blockIdx.x * 256 + threadIdx.x;
  bool ok = omega[e] != 0.f;
  unsigned long long mask = __ballot(ok);
  if ((threadIdx.x & 63) == 0) obit[e >> 6] = mask;
}

// ---------------------------------------------------------------------------
// Fused Q/K/V projection GEMM. Grid (24, 32): blockIdx.x/8 selects Q|K|V.
// Q,K: hi/lo split (3 MFMAs, fp32-level accuracy); V: plain bf16.
// 768 blocks = 3 blocks/CU (vs 256 = 1/CU when dispatched separately —
// R9 showed Occupancy 10.6%, MfmaUtil 13%: barrier drain fully exposed).
// ---------------------------------------------------------------------------
__global__ __launch_bounds__(256) void mfma_gemm_qkv(
    const unsigned short* __restrict__ xh, const unsigned short* __restrict__ xl,
    const unsigned short* __restrict__ wqh, const unsigned short* __restrict__ wql,
    const unsigned short* __restrict__ wkh, const unsigned short* __restrict__ wkl,
    const unsigned short* __restrict__ wvh,
    const float* __restrict__ bq, const float* __restrict__ bk,
    const float* __restrict__ bv,
    unsigned short* __restrict__ qoh, unsigned short* __restrict__ qol,
    unsigned short* __restrict__ koh, unsigned short* __restrict__ kol,
    unsigned short* __restrict__ voh) {
  __shared__ unsigned short tiles[4 * 4096];   // [tile][128 rows][32 cols]
  const int t = threadIdx.x;
  const int wave = t >> 6, lane = t & 63;
  const int which = blockIdx.x >> 3;           // 0=Q, 1=K, 2=V (block-uniform)
  const int n0 = (blockIdx.x & 7) * 128;
  const int i0 = blockIdx.y * 128;
  const int K = D_, N = D_;
  const int wm = wave >> 1, wn = wave & 1;
  const int m = lane & 15, quad = lane >> 4;

  const unsigned short* Wh = (which == 0) ? wqh : (which == 1) ? wkh : wvh;
  const unsigned short* Wl = (which == 0) ? wql : wkl;     // dead for V
  const float* bias = (which == 0) ? bq : (which == 1) ? bk : bv;
  unsigned short* Chi = (which == 0) ? qoh : (which == 1) ? koh : voh;
  unsigned short* Clo = (which == 0) ? qol : (which == 1) ? kol : nullptr;
  const bool split = (which < 2);
  const int ntiles = split ? 4 : 2;

  const unsigned short* gb[4];
  gb[0] = xh + (size_t)i0 * K;
  gb[1] = Wh + (size_t)n0 * K;
  gb[2] = xl + (size_t)i0 * K;
  gb[3] = Wl + (size_t)n0 * K;

  f32x4 acc[4][4] = {};

  for (int k0 = 0; k0 < K; k0 += 32) {
    __syncthreads();
    for (int cc = wave; cc < ntiles * 8; cc += 4) {
      int tile = cc >> 3, c = cc & 7;
      int s = (c << 6) + lane;
      int row = s >> 2;
      int cq = (s & 3) ^ ((s >> 3) & 3);          // XOR swizzle of k-quad
      const unsigned short* g = gb[tile] + (size_t)row * K + k0 + (cq << 3);
      unsigned short* l = &tiles[tile * 4096 + (s << 3)];
      __builtin_amdgcn_global_load_lds((const __attribute__((address_space(1))) void*)g,
                                       (__attribute__((address_space(3))) void*)l,
                                       16, 0, 0);
    }
    __syncthreads();

    bf16x8 afh[4], bfh[4];
#pragma unroll
    for (int mt = 0; mt < 4; ++mt) {
      int r = wm * 64 + mt * 16 + m;
      afh[mt] = *(const bf16x8*)&tiles[0 * 4096 + r * 32 + ((quad ^ ((r >> 1) & 3)) << 3)];
    }
#pragma unroll
    for (int nt = 0; nt < 4; ++nt) {
      int r = wn * 64 + nt * 16 + m;
      bfh[nt] = *(const bf16x8*)&tiles[1 * 4096 + r * 32 + ((quad ^ ((r >> 1) & 3)) << 3)];
    }
    if (split) {
      bf16x8 afl[4], bfl[4];
#pragma unroll
      for (int mt = 0; mt < 4; ++mt) {
        int r = wm * 64 + mt * 16 + m;
        afl[mt] = *(const bf16x8*)&tiles[2 * 4096 + r * 32 + ((quad ^ ((r >> 1) & 3)) << 3)];
      }
#pragma unroll
      for (int nt = 0; nt < 4; ++nt) {
        int r = wn * 64 + nt * 16 + m;
        bfl[nt] = *(const bf16x8*)&tiles[3 * 4096 + r * 32 + ((quad ^ ((r >> 1) & 3)) << 3)];
      }
#pragma unroll
      for (int mt = 0; mt < 4; ++mt)
#pragma unroll
        for (int nt = 0; nt < 4; ++nt) {
          acc[mt][nt] = MFMA16(afh[mt], bfh[nt], acc[mt][nt]);
          acc[mt][nt] = MFMA16(afl[mt], bfh[nt], acc[mt][nt]);
          acc[mt][nt] = MFMA16(afh[mt], bfl[nt], acc[mt][nt]);
        }
    } else {
#pragma unroll
      for (int mt = 0; mt < 4; ++mt)
#pragma unroll
        for (int nt = 0; nt < 4; ++nt)
          acc[mt][nt] = MFMA16(afh[mt], bfh[nt], acc[mt][nt]);
    }
  }

  // epilogue: C/D layout col=lane&15, row=quad*4+reg
  float bvv[4];
#pragma unroll
  for (int nt = 0; nt < 4; ++nt) bvv[nt] = bias[n0 + wn * 64 + nt * 16 + m];
#pragma unroll
  for (int mt = 0; mt < 4; ++mt) {
    int rbase = i0 + wm * 64 + mt * 16 + quad * 4;
#pragma unroll
    for (int nt = 0; nt < 4; ++nt) {
      int col = n0 + wn * 64 + nt * 16 + m;
#pragma unroll
      for (int r = 0; r < 4; ++r) {
        float val = acc[mt][nt][r] + bvv[nt];
        size_t idx = (size_t)(rbase + r) * N + col;
        unsigned short hv = f2bf(val);
        Chi[idx] = hv;
        if (Clo) Clo[idx] = f2bf(val - bf2f(hv));
      }
    }
  }
}

// ---------------------------------------------------------------------------
// Plain bf16 MFMA GEMM (O projection): out fp32.
// ---------------------------------------------------------------------------
__global__ __launch_bounds__(256) void mfma_gemm_o(const unsigned short* __restrict__ Ah,
                                                   const unsigned short* __restrict__ Wh,
                                                   const float* __restrict__ bias,
                                                   float* __restrict__ C,
                                                   int M, int N, int K) {
  __shared__ unsigned short tiles[2 * 4096];
  const int t = threadIdx.x;
  const int wave = t >> 6, lane = t & 63;
  const int i0 = blockIdx.y * 128, n0 = blockIdx.x * 128;
  const int wm = wave >> 1, wn = wave & 1;
  const int m = lane & 15, quad = lane >> 4;

  const unsigned short* gb[2];
  gb[0] = Ah + (size_t)i0 * K;
  gb[1] = Wh + (size_t)n0 * K;

  f32x4 acc[4][4] = {};
  for (int k0 = 0; k0 < K; k0 += 32) {
    __syncthreads();
    for (int cc = wave; cc < 16; cc += 4) {
      int tile = cc >> 3, c = cc & 7;
      int s = (c << 6) + lane;
      int row = s >> 2;
      int cq = (s & 3) ^ ((s >> 3) & 3);
      const unsigned short* g = gb[tile] + (size_t)row * K + k0 + (cq << 3);
      unsigned short* l = &tiles[tile * 4096 + (s << 3)];
      __builtin_amdgcn_global_load_lds((const __attribute__((address_space(1))) void*)g,
                                       (__attribute__((address_space(3))) void*)l,
                                       16, 0, 0);
    }
    __syncthreads();
    bf16x8 afh[4], bfh[4];
#pragma unroll
    for (int mt = 0; mt < 4; ++mt) {
      int r = wm * 64 + mt * 16 + m;
      afh[mt] = *(const bf16x8*)&tiles[0 * 4096 + r * 32 + ((quad ^ ((r >> 1) & 3)) << 3)];
    }
#pragma unroll
    for (int nt = 0; nt < 4; ++nt) {
      int r = wn * 64 + nt * 16 + m;
      bfh[nt] = *(const bf16x8*)&tiles[1 * 4096 + r * 32 + ((quad ^ ((r >> 1) & 3)) << 3)];
    }
#pragma unroll
    for (int mt = 0; mt < 4; ++mt)
#pragma unroll
      for (int nt = 0; nt < 4; ++nt)
        acc[mt][nt] = MFMA16(afh[mt], bfh[nt], acc[mt][nt]);
  }

  float bvv[4];
#pragma unroll
  for (int nt = 0; nt < 4; ++nt) bvv[nt] = bias[n0 + wn * 64 + nt * 16 + m];
#pragma unroll
  for (int mt = 0; mt < 4; ++mt) {
    int rbase = i0 + wm * 64 + mt * 16 + quad * 4;
#pragma unroll
    for (int nt = 0; nt < 4; ++nt) {
      int col = n0 + wn * 64 + nt * 16 + m;
#pragma unroll
      for (int r = 0; r < 4; ++r)
        C[(size_t)(rbase + r) * N + col] = acc[mt][nt][r] + bvv[nt];
    }
  }
}

// ---------------------------------------------------------------------------
// ts8[b][g][d] = sum over j in [8g, 8g+8) of v[b][j][d]  (bf16 v input)
// ---------------------------------------------------------------------------
__global__ void ts8_kernel(const unsigned short* __restrict__ vh, float* __restrict__ ts8) {
  int idx = blockIdx.x * 256 + threadIdx.x;  // (b*256+g)*D_ + d
  int d = idx % D_;
  int bg = idx / D_;
  int g = bg % 256;
  int b = bg / 256;
  const unsigned short* p = vh + (size_t)(b * S_ + g * 8) * D_ + d;
  float s = 0.f;
#pragma unroll
  for (int j = 0; j < 8; ++j) s += bf2f(p[(size_t)j * D_]);
  ts8[idx] = s;
}

// ---------------------------------------------------------------------------
// ts64[b][T][d] = sum of 8 ts8 groups   (T in [0,32))
// ---------------------------------------------------------------------------
__global__ void ts64_kernel(const float* __restrict__ ts8, float* __restrict__ ts64) {
  int idx = blockIdx.x * 256 + threadIdx.x;  // (b*32+T)*D_ + d
  int d = idx % D_;
  int bT = idx / D_;
  int T = bT % 32;
  int b = bT / 32;
  float s = 0.f;
#pragma unroll
  for (int u = 0; u < 8; ++u) s += ts8[((size_t)b * 256 + T * 8 + u) * D_ + d];
  ts64[idx] = s;
}

// ---------------------------------------------------------------------------
// tsp[b][T][d] = sum of ts64[b][T'<T][d]   (T in [0,33]; T=32 -> total)
// ---------------------------------------------------------------------------
__global__ void tsp2_kernel(const float* __restrict__ ts64, float* __restrict__ tsp) {
  int idx = blockIdx.x * 256 + threadIdx.x;  // (b*33+T)*D_ + d
  int d = idx % D_;
  int bT = idx / D_;
  int T = bT % 33;
  int b = bT / 33;
  float s = 0.f;
  for (int u = 0; u < T; ++u) s += ts64[((size_t)b * 32 + u) * D_ + d];
  tsp[idx] = s;
}

// ---------------------------------------------------------------------------
// bandmask[b*S+i] bit dlt = 1 iff j=i-dlt >= 0 and omega unmasked (via obit)
// ---------------------------------------------------------------------------
__global__ __launch_bounds__(256) void bandmask_kernel(const int* __restrict__ ids,
                                                       const unsigned long long* __restrict__ obit,
                                                       unsigned long long* __restrict__ bm) {
  int row = blockIdx.x * 4 + (threadIdx.x >> 6);
  int lane = threadIdx.x & 63;
  int b = row / S_, i = row % S_;
  int idi = ids[row];
  int j = i - lane;
  bool ok = false;
  if (j >= 0) {
    int idj = ids[b * S_ + j];
    ok = (obit[((size_t)idi << 6) + (idj >> 6)] >> (idj & 63)) & 1ull;
  }
  unsigned long long mask = __ballot(ok);
  if (lane == 0) bm[row] = mask;
}

// ---------------------------------------------------------------------------
// farsum (bf16 out) / c0 — prefix hierarchy + bit-packed omega
// ---------------------------------------------------------------------------
__global__ __launch_bounds__(256) void farsum_kernel(const unsigned short* __restrict__ vh,
                                                     const float* __restrict__ ts8,
                                                     const float* __restrict__ tsp,
                                                     const int* __restrict__ ids,
                                                     const unsigned long long* __restrict__ obit,
                                                     unsigned short* __restrict__ farsum,
                                                     int* __restrict__ c0) {
  const int b = blockIdx.x / S_;
  const int i = blockIdx.x % S_;
  const int t = threadIdx.x;
  if (i < 64) {
    if (t == 0) c0[blockIdx.x] = 0;
    return;
  }
  const int jmax = i - 64;
  const int F = jmax + 1;
  const int d0 = t * 4;
  const int T = F >> 6;
  const int G8 = (F & 63) >> 3;

  float4 acc = *(const float4*)(tsp + ((size_t)b * 33 + T) * D_ + d0);
  for (int u = 0; u < G8; ++u) {
    float4 x = *(const float4*)(ts8 + ((size_t)b * 256 + T * 8 + u) * D_ + d0);
    acc.x += x.x; acc.y += x.y; acc.z += x.z; acc.w += x.w;
  }
  for (int j = (T << 6) + (G8 << 3); j <= jmax; ++j) {
    ushort4 x = *(const ushort4*)(vh + ((size_t)(b * S_) + j) * D_ + d0);
    acc.x += bf2f(x.x); acc.y += bf2f(x.y);
    acc.z += bf2f(x.z); acc.w += bf2f(x.w);
  }

  __shared__ int list[256];
  __shared__ int cnt;
  const int idi = ids[b * S_ + i];
  const unsigned long long* orow = obit + ((size_t)idi << 6);
  int nmask = 0;
  for (int base = 0; base < F; base += 256) {
    if (t == 0) cnt = 0;
    __syncthreads();
    int j = base + t;
    if (j <= jmax) {
      int idj = ids[b * S_ + j];
      if (!((orow[idj >> 6] >> (idj & 63)) & 1ull)) list[atomicAdd(&cnt, 1)] = j;
    }
    __syncthreads();
    int c = cnt;
    nmask += c;
    for (int mm = 0; mm < c; ++mm) {
      int jm = list[mm];
      ushort4 x = *(const ushort4*)(vh + ((size_t)(b * S_) + jm) * D_ + d0);
      acc.x -= bf2f(x.x); acc.y -= bf2f(x.y);
      acc.z -= bf2f(x.z); acc.w -= bf2f(x.w);
    }
    __syncthreads();
  }
  ushort4 o;
  o.x = f2bf(acc.x); o.y = f2bf(acc.y); o.z = f2bf(acc.z); o.w = f2bf(acc.w);
  *(ushort4*)(farsum + (size_t)(b * S_ + i) * D_ + d0) = o;
  if (t == 0) c0[blockIdx.x] = F - nmask;
}

// ---------------------------------------------------------------------------
// MFMA flash-style banded attention (unchanged from R8/R9).
// ---------------------------------------------------------------------------
__global__ __launch_bounds__(256) void attn3_kernel(
    const unsigned short* __restrict__ qh, const unsigned short* __restrict__ ql,
    const unsigned short* __restrict__ kh, const unsigned short* __restrict__ kl,
    const unsigned short* __restrict__ vh, const unsigned short* __restrict__ farsum,
    const int* __restrict__ c0arr, const float* __restrict__ tsp,
    const unsigned long long* __restrict__ bm, const float* __restrict__ gamma,
    unsigned short* __restrict__ out) {
  const int h = blockIdx.x, i0 = blockIdx.y * 64, b = blockIdx.z;
  __shared__ unsigned short Qhs[64][72], Qls[64][72], Khs[64][72], KlP[64][72], Vt[64][72];
  __shared__ float mrow[64], lrow[64], arow[64], Mband[64];
  __shared__ float rmaxw[4][32], rsumw[4][32];
  __shared__ unsigned long long bmr[64];
  __shared__ int c0r[64];
  const int t = threadIdx.x, lane = t & 63, wave = t >> 6;
  const int m = lane & 15, quad = lane >> 4;
  const int wm = wave >> 1, wn = wave & 1;

  for (int c = t; c < 1024; c += 256) {
    int r = c >> 4, d4 = (c & 15) << 2;
    size_t g = ((size_t)(b * S_) + i0 + r) * D_ + h * 64 + d4;
    *(ushort4*)&Qhs[r][d4] = *(const ushort4*)(qh + g);
    *(ushort4*)&Qls[r][d4] = *(const ushort4*)(ql + g);
  }
  if (t < 64) {
    float delta = (float)t;
    float ld = logf(delta + 1.f);
    float cs = 0.f;
#pragma unroll
    for (int z = 0; z < NZ_; ++z) cs += cosf(gamma[z] * ld);
    Mband[t] = expf(-delta) * cs * 0.125f;
    int grow = b * S_ + i0 + t;
    bmr[t] = bm[grow];
    int c0v = c0arr[grow];
    c0r[t] = c0v;
    mrow[t] = (c0v > 0) ? 0.f : -FLT_MAX;
    lrow[t] = 0.f;
  }
  f32x4 accO[2][2] = {};

  for (int pass = 0; pass < 2; ++pass) {
    const int jt0 = i0 + (pass - 1) * 64;
    if (jt0 < 0) continue;
    __syncthreads();
    for (int c = t; c < 1024; c += 256) {
      int r = c >> 4, d4 = (c & 15) << 2;
      size_t g = ((size_t)(b * S_) + jt0 + r) * D_ + h * 64 + d4;
      *(ushort4*)&Khs[r][d4] = *(const ushort4*)(kh + g);
      *(ushort4*)&KlP[r][d4] = *(const ushort4*)(kl + g);
      ushort4 vv = *(const ushort4*)(vh + g);
      Vt[d4 + 0][r] = vv.x; Vt[d4 + 1][r] = vv.y;
      Vt[d4 + 2][r] = vv.z; Vt[d4 + 3][r] = vv.w;
    }
    __syncthreads();
    f32x4 accS[2][2] = {};
#pragma unroll
    for (int kc = 0; kc < 2; ++kc) {
      bf16x8 aH[2], aL[2], bH[2], bL[2];
#pragma unroll
      for (int mt = 0; mt < 2; ++mt) {
        aH[mt] = *(const bf16x8*)&Qhs[wm * 32 + mt * 16 + m][kc * 32 + quad * 8];
        aL[mt] = *(const bf16x8*)&Qls[wm * 32 + mt * 16 + m][kc * 32 + quad * 8];
      }
#pragma unroll
      for (int nt = 0; nt < 2; ++nt) {
        bH[nt] = *(const bf16x8*)&Khs[wn * 32 + nt * 16 + m][kc * 32 + quad * 8];
        bL[nt] = *(const bf16x8*)&KlP[wn * 32 + nt * 16 + m][kc * 32 + quad * 8];
      }
#pragma unroll
      for (int mt = 0; mt < 2; ++mt)
#pragma unroll
        for (int nt = 0; nt < 2; ++nt) {
          accS[mt][nt] = MFMA16(aH[mt], bH[nt], accS[mt][nt]);
          accS[mt][nt] = MFMA16(aL[mt], bH[nt], accS[mt][nt]);
          accS[mt][nt] = MFMA16(aH[mt], bL[nt], accS[mt][nt]);
        }
    }
    float rmx[2][4];
#pragma unroll
    for (int mt = 0; mt < 2; ++mt)
#pragma unroll
      for (int r = 0; r < 4; ++r) rmx[mt][r] = -FLT_MAX;
#pragma unroll
    for (int mt = 0; mt < 2; ++mt)
#pragma unroll
      for (int nt = 0; nt < 2; ++nt)
#pragma unroll
        for (int r = 0; r < 4; ++r) {
          int il = wm * 32 + mt * 16 + quad * 4 + r;
          int jl = wn * 32 + nt * 16 + m;
          int dlt = (pass == 0) ? (il + 64 - jl) : (il - jl);
          float s = -FLT_MAX;
          if (dlt >= 0 && dlt < 64 && ((bmr[il] >> dlt) & 1ull))
            s = accS[mt][nt][r] * Mband[dlt];
          accS[mt][nt][r] = s;
          rmx[mt][r] = fmaxf(rmx[mt][r], s);
        }
#pragma unroll
    for (int off = 1; off < 16; off <<= 1)
#pragma unroll
      for (int mt = 0; mt < 2; ++mt)
#pragma unroll
        for (int r = 0; r < 4; ++r)
          rmx[mt][r] = fmaxf(rmx[mt][r], __shfl_xor(rmx[mt][r], off));
    if (m == 0)
#pragma unroll
      for (int mt = 0; mt < 2; ++mt)
#pragma unroll
        for (int r = 0; r < 4; ++r)
          rmaxw[wave][mt * 16 + quad * 4 + r] = rmx[mt][r];
    __syncthreads();
    if (t < 64) {
      int wmw = t >> 5, idx = t & 31;
      float tmax = fmaxf(rmaxw[wmw * 2][idx], rmaxw[wmw * 2 + 1][idx]);
      float mold = mrow[t], mnew = fmaxf(mold, tmax);
      arow[t] = expf(mold - mnew);
      mrow[t] = mnew;
    }
    __syncthreads();
    float rs[2][4] = {};
#pragma unroll
    for (int mt = 0; mt < 2; ++mt)
#pragma unroll
      for (int nt = 0; nt < 2; ++nt)
#pragma unroll
        for (int r = 0; r < 4; ++r) {
          int il = wm * 32 + mt * 16 + quad * 4 + r;
          int jl = wn * 32 + nt * 16 + m;
          float s = accS[mt][nt][r];
          float p = (s > -1e37f) ? expf(s - mrow[il]) : 0.f;
          rs[mt][r] += p;
          KlP[il][jl] = f2bf(p);
        }
#pragma unroll
    for (int off = 1; off < 16; off <<= 1)
#pragma unroll
      for (int mt = 0; mt < 2; ++mt)
#pragma unroll
        for (int r = 0; r < 4; ++r)
          rs[mt][r] += __shfl_xor(rs[mt][r], off);
    if (m == 0)
#pragma unroll
      for (int mt = 0; mt < 2; ++mt)
#pragma unroll
        for (int r = 0; r < 4; ++r)
          rsumw[wave][mt * 16 + quad * 4 + r] = rs[mt][r];
#pragma unroll
    for (int mt = 0; mt < 2; ++mt)
#pragma unroll
      for (int r = 0; r < 4; ++r) {
        float al = arow[wm * 32 + mt * 16 + quad * 4 + r];
        accO[mt][0][r] *= al;
        accO[mt][1][r] *= al;
      }
    __syncthreads();
    if (t < 64) {
      int wmw = t >> 5, idx = t & 31;
      lrow[t] = lrow[t] * arow[t] + rsumw[wmw * 2][idx] + rsumw[wmw * 2 + 1][idx];
    }
#pragma unroll
    for (int kc = 0; kc < 2; ++kc) {
      bf16x8 aP[2], bV[2];
#pragma unroll
      for (int mt = 0; mt < 2; ++mt)
        aP[mt] = *(const bf16x8*)&KlP[wm * 32 + mt * 16 + m][kc * 32 + quad * 8];
#pragma unroll
      for (int nt = 0; nt < 2; ++nt)
        bV[nt] = *(const bf16x8*)&Vt[wn * 32 + nt * 16 + m][kc * 32 + quad * 8];
#pragma unroll
      for (int mt = 0; mt < 2; ++mt)
#pragma unroll
        for (int nt = 0; nt < 2; ++nt)
          accO[mt][nt] = MFMA16(aP[mt], bV[nt], accO[mt][nt]);
    }
  }
  __syncthreads();
#pragma unroll
  for (int mt = 0; mt < 2; ++mt)
#pragma unroll
    for (int r = 0; r < 4; ++r) {
      int il = wm * 32 + mt * 16 + quad * 4 + r;
      int gi = i0 + il;
      float mv = mrow[il], l = lrow[il];
      int C0 = c0r[il];
      float efar = (C0 > 0) ? expf(-mv) : 0.f;
      float denom = l + (float)C0 * efar;
      bool degen = (l == 0.f && C0 == 0);
      if (degen) denom = (float)S_;
      float inv = 1.f / denom;
#pragma unroll
      for (int nt = 0; nt < 2; ++nt) {
        int d = wn * 32 + nt * 16 + m;
        size_t base = ((size_t)(b * S_) + gi) * D_ + h * 64 + d;
        float o = accO[mt][nt][r];
        if (C0 > 0) o += efar * bf2f(farsum[base]);
        if (degen) o = tsp[((size_t)b * 33 + 32) * D_ + h * 64 + d];
        out[base] = f2bf(o * inv);
      }
    }
}

// ---------------------------------------------------------------------------
extern "C" void kernel_launch(void* const* d_in, const int* in_sizes, int n_in,
                              void* d_out, int out_size, void* d_ws, size_t ws_size,
                              hipStream_t stream) {
  const float* x     = (const float*)d_in[0];
  const float* wq    = (const float*)d_in[1];
  const float* bq    = (const float*)d_in[2];
  const float* wk    = (const float*)d_in[3];
  const float* bk    = (const float*)d_in[4];
  const float* wv    = (const float*)d_in[5];
  const float* bv    = (const float*)d_in[6];
  const float* wo    = (const float*)d_in[7];
  const float* bo    = (const float*)d_in[8];
  const float* omega = (const float*)d_in[9];
  const float* gamma = (const float*)d_in[10];
  const int*   ids   = (const int*)d_in[11];
  float* out = (float*)d_out;

  // Workspace ~76 MB (watermark: keep < 84 MB — R3's 96.8 MB corrupted
  // harness memory).
  char* ws = (char*)d_ws;
  const size_t SZH = (size_t)BS_ * D_ * 2;                  // 8.39 MB bf16 unit
  const size_t WH  = (size_t)D_ * D_ * 2;                   // 2.10 MB
  unsigned short* qhb = (unsigned short*)(ws);
  unsigned short* qlb = (unsigned short*)(ws + 1 * SZH);
  unsigned short* khb = (unsigned short*)(ws + 2 * SZH);
  unsigned short* klb = (unsigned short*)(ws + 3 * SZH);
  unsigned short* vhb = (unsigned short*)(ws + 4 * SZH);
  unsigned short* xl    = (unsigned short*)(ws + 5 * SZH);  // dies after QKV-GEMM
  unsigned short* fsumh = xl;                               // aliases xl
  unsigned short* xh    = (unsigned short*)(ws + 6 * SZH);
  unsigned short* ah    = xh;                               // attn out, after QKV-GEMM
  char* wp = ws + 7 * SZH;
  unsigned short* wqh = (unsigned short*)(wp);
  unsigned short* wql = (unsigned short*)(wp + 1 * WH);
  unsigned short* wkh = (unsigned short*)(wp + 2 * WH);
  unsigned short* wkl = (unsigned short*)(wp + 3 * WH);
  unsigned short* wvh = (unsigned short*)(wp + 4 * WH);
  unsigned short* woh = (unsigned short*)(wp + 5 * WH);
  char* tail = wp + 6 * WH;
  unsigned long long* obit = (unsigned long long*)tail;               // 2 MB
  float* ts8  = (float*)(tail + (size_t)V_ * 64 * 8);                 // 2.10 MB
  float* ts64 = (float*)((char*)ts8 + (size_t)B_ * 256 * D_ * 4);     // 0.26 MB
  float* tsp  = (float*)((char*)ts64 + (size_t)B_ * 32 * D_ * 4);     // 0.27 MB
  int* c0 = (int*)((char*)tsp + (size_t)B_ * 33 * D_ * 4);
  unsigned long long* bmask = (unsigned long long*)((char*)c0 + (size_t)BS_ * 4);

  split_kernel<true><<<(BS_ * D_) / 1024, 256, 0, stream>>>(x, xh, xl);
  omega_pack_kernel<<<(V_ * V_) / 256, 256, 0, stream>>>(omega, obit);
  split_w4_kernel<<<(4 * D_ * D_) / 1024, 256, 0, stream>>>(wq, wk, wv, wo,
                                                            wqh, wql, wkh, wkl, wvh, woh);

  // Fused Q/K/V projection: 768 blocks = 3 blocks/CU.
  mfma_gemm_qkv<<<dim3(24, 32), 256, 0, stream>>>(xh, xl, wqh, wql, wkh, wkl, wvh,
                                                  bq, bk, bv, qhb, qlb, khb, klb, vhb);

  ts8_kernel<<<(B_ * 256 * D_) / 256, 256, 0, stream>>>(vhb, ts8);
  ts64_kernel<<<(B_ * 32 * D_) / 256, 256, 0, stream>>>(ts8, ts64);
  tsp2_kernel<<<(B_ * 33 * D_) / 256, 256, 0, stream>>>(ts64, tsp);
  bandmask_kernel<<<(B_ * S_) / 4, 256, 0, stream>>>(ids, obit, bmask);
  farsum_kernel<<<B_ * S_, 256, 0, stream>>>(vhb, ts8, tsp, ids, obit, fsumh, c0);
  attn3_kernel<<<dim3(H_, S_ / 64, B_), 256, 0, stream>>>(qhb, qlb, khb, klb, vhb, fsumh, c0,
                                                          tsp, bmask, gamma, ah);

  mfma_gemm_o<<<dim3(D_ / 128, BS_ / 128), 256, 0, stream>>>(ah, woh, bo, out, BS_, D_, D_);
}